// Round 20
// baseline (258.173 us; speedup 1.0000x reference)
//
#include <hip/hip_runtime.h>
#include <hip/hip_bf16.h>

// Problem dims (fixed by reference setup_inputs)
#define NN 32768
#define HH 768
#define HEADS 2
#define EE 131072
#define HC (HEADS*HH)      // 1536
#define ETOT (EE + NN)     // 163840 (edges + self loops)
#define NEG_SLOPE 0.2f
#define GK 768             // GEMM K
#define GNF 3072           // fused GEMM N ([W_l | W_r] cols)
#define NCH (GK/16)        // 48 k-chunks of 16 bytes
#define WBLK 1152          // W-role blocks per weight (48 n-tiles x 24 k-tiles)
#define EBLK 1792          // emb-role blocks

typedef float f32x16 __attribute__((ext_vector_type(16)));
typedef int i32x8 __attribute__((ext_vector_type(8)));

// ======== fused prep: W_l-chunk | W_r-chunk | emb-chunk + zero + mask-count ==
__global__ __launch_bounds__(256) void prep(
    const float* __restrict__ W_l, const float* __restrict__ W_r,
    const float* __restrict__ emb, const int* __restrict__ mask,
    unsigned char* __restrict__ B8c, unsigned char* __restrict__ A8c,
    float* __restrict__ zbase, int nz, float* __restrict__ partials) {
  int b = blockIdx.x, tid = threadIdx.x;
  if (b < 2 * WBLK) {
    // ---- W role (transpose+convert to chunked fp8) ----
    const float* W = (b < WBLK) ? W_l : W_r;
    int coff = (b < WBLK) ? 0 : HC;
    int b2 = (b < WBLK) ? b : b - WBLK;
    __shared__ float tile[32][33];
    int n0 = (b2 % 48) * 32, k0 = (b2 / 48) * 32;
    int tx = tid & 31, ty = tid >> 5;  // 32 x 8
#pragma unroll
    for (int s = 0; s < 4; ++s)
      tile[ty + s * 8][tx] = W[(size_t)(k0 + ty + s * 8) * HC + n0 + tx];
    __syncthreads();
#pragma unroll
    for (int s = 0; s < 4; ++s) {
      int k = k0 + tx, n = n0 + ty + s * 8;
      int pk = __builtin_amdgcn_cvt_pk_fp8_f32(tile[tx][ty + s * 8], 0.f, 0, false);
      B8c[((size_t)(k >> 4) * GNF + coff + n) * 16 + (k & 15)] = (unsigned char)(pk & 0xff);
    }
    return;
  }
  // ---- emb role ----
  int ridx = b - 2 * WBLK;
  int i0 = ridx * 256 + tid;
  const int st = EBLK * 256;
  const int total = NN * NCH;
  for (int i = i0; i < total; i += st) {
    int n = i & (NN - 1), q = i >> 15;
    const float* src = emb + (size_t)n * GK + q * 16;
    float4 a = *(const float4*)(src);
    float4 bb = *(const float4*)(src + 4);
    float4 c = *(const float4*)(src + 8);
    float4 d = *(const float4*)(src + 12);
    int pk0 = 0, pk1 = 0, pk2 = 0, pk3 = 0;
    pk0 = __builtin_amdgcn_cvt_pk_fp8_f32(a.x, a.y, pk0, false);
    pk0 = __builtin_amdgcn_cvt_pk_fp8_f32(a.z, a.w, pk0, true);
    pk1 = __builtin_amdgcn_cvt_pk_fp8_f32(bb.x, bb.y, pk1, false);
    pk1 = __builtin_amdgcn_cvt_pk_fp8_f32(bb.z, bb.w, pk1, true);
    pk2 = __builtin_amdgcn_cvt_pk_fp8_f32(c.x, c.y, pk2, false);
    pk2 = __builtin_amdgcn_cvt_pk_fp8_f32(c.z, c.w, pk2, true);
    pk3 = __builtin_amdgcn_cvt_pk_fp8_f32(d.x, d.y, pk3, false);
    pk3 = __builtin_amdgcn_cvt_pk_fp8_f32(d.z, d.w, pk3, true);
    int4 pk; pk.x = pk0; pk.y = pk1; pk.z = pk2; pk.w = pk3;
    *(int4*)(A8c + (size_t)i * 16) = pk;
  }
  for (int i = i0; i < nz; i += st) zbase[i] = 0.f;
  float local = 0.f;
  for (int i = i0; i < NN; i += st) local += (mask[i] != 0) ? 1.f : 0.f;
#pragma unroll
  for (int off = 32; off; off >>= 1) local += __shfl_down(local, off);
  __shared__ float wsum[4];
  if ((tid & 63) == 0) wsum[tid >> 6] = local;
  __syncthreads();
  if (tid == 0) partials[ridx] = wsum[0] + wsum[1] + wsum[2] + wsum[3];
}

// ======== GEMM (MX-fp8, barrier-free, 64x128 wave tile): control, R16 ========
__global__ __launch_bounds__(256) void gemm_fp8(
    const unsigned char* __restrict__ Ac, const unsigned char* __restrict__ Bc,
    unsigned char* __restrict__ X) {
  __shared__ unsigned char cb[128 * 264];
  int tid = threadIdx.x, lane = tid & 63, wv = tid >> 6;
  int wvr = wv >> 1, wvc = wv & 1;
  int b = blockIdx.x;
  int xcd = b & 7, loc = b >> 3;        // loc 0..383
  int m_blk = xcd * 32 + loc / 12, n_blk = loc % 12;
  int m0 = m_blk * 128, n0 = n_blk * 256;

  int qb = (lane >> 5) * 2;
  int arow = m0 + wvr * 64 + (lane & 31);
  int brow = n0 + wvc * 128 + (lane & 31);
  const unsigned char* pA = Ac + ((size_t)qb * NN + arow) * 16;
  const unsigned char* pB = Bc + ((size_t)qb * GNF + brow) * 16;
  const size_t stA = (size_t)4 * NN * 16;
  const size_t stB = (size_t)4 * GNF * 16;

  int4 bA[2][2][2], bB[2][4][2];
  f32x16 acc[2][4] = {};

#define ISSUE(pp_, it_) {                                               \
    const unsigned char* a_ = pA + (size_t)(it_) * stA;                 \
    const unsigned char* b_ = pB + (size_t)(it_) * stB;                 \
    _Pragma("unroll") for (int mg = 0; mg < 2; ++mg) {                  \
      bA[pp_][mg][0] = *(const int4*)(a_ + mg * 512);                   \
      bA[pp_][mg][1] = *(const int4*)(a_ + mg * 512 + (size_t)NN * 16); } \
    _Pragma("unroll") for (int ng = 0; ng < 4; ++ng) {                  \
      bB[pp_][ng][0] = *(const int4*)(b_ + ng * 512);                   \
      bB[pp_][ng][1] = *(const int4*)(b_ + ng * 512 + (size_t)GNF * 16); } }

#define MM(pp_) {                                                       \
    i32x8 bfr[4];                                                       \
    _Pragma("unroll") for (int ng = 0; ng < 4; ++ng) {                  \
      bfr[ng][0] = bB[pp_][ng][0].x; bfr[ng][1] = bB[pp_][ng][0].y;     \
      bfr[ng][2] = bB[pp_][ng][0].z; bfr[ng][3] = bB[pp_][ng][0].w;     \
      bfr[ng][4] = bB[pp_][ng][1].x; bfr[ng][5] = bB[pp_][ng][1].y;     \
      bfr[ng][6] = bB[pp_][ng][1].z; bfr[ng][7] = bB[pp_][ng][1].w; }   \
    _Pragma("unroll") for (int mg = 0; mg < 2; ++mg) {                  \
      i32x8 af;                                                         \
      af[0] = bA[pp_][mg][0].x; af[1] = bA[pp_][mg][0].y;               \
      af[2] = bA[pp_][mg][0].z; af[3] = bA[pp_][mg][0].w;               \
      af[4] = bA[pp_][mg][1].x; af[5] = bA[pp_][mg][1].y;               \
      af[6] = bA[pp_][mg][1].z; af[7] = bA[pp_][mg][1].w;               \
      _Pragma("unroll") for (int ng = 0; ng < 4; ++ng)                  \
        acc[mg][ng] = __builtin_amdgcn_mfma_scale_f32_32x32x64_f8f6f4(  \
            bfr[ng], af, acc[mg][ng], 0, 0,                             \
            0, 0x7F7F7F7F, 0, 0x7F7F7F7F); } }

  ISSUE(0, 0);
  ISSUE(1, 1);
#pragma unroll
  for (int t = 0; t < 12; ++t) {
    const int pp = t & 1;
    MM(pp);
    if (t + 2 < 12) ISSUE(pp, t + 2);
  }
#undef ISSUE
#undef MM

#pragma unroll
  for (int mg = 0; mg < 2; ++mg) {
    int m = wvr * 64 + mg * 32 + (lane & 31);
#pragma unroll
    for (int ng = 0; ng < 4; ++ng) {
      int nb = wvc * 128 + ng * 32 + (lane >> 5) * 4;
#pragma unroll
      for (int rq = 0; rq < 4; ++rq) {
        int pk = 0;
        pk = __builtin_amdgcn_cvt_pk_fp8_f32(acc[mg][ng][rq * 4 + 0],
                                             acc[mg][ng][rq * 4 + 1], pk, false);
        pk = __builtin_amdgcn_cvt_pk_fp8_f32(acc[mg][ng][rq * 4 + 2],
                                             acc[mg][ng][rq * 4 + 3], pk, true);
        *(int*)&cb[m * 264 + nb + rq * 8] = pk;
      }
    }
  }
  __syncthreads();
  {
    int r = tid >> 1, hf = tid & 1;
    const unsigned char* src = &cb[r * 264 + hf * 128];
    unsigned char* dst = X + (size_t)(m0 + r) * GNF + n0 + hf * 128;
#pragma unroll
    for (int q = 0; q < 16; ++q)
      *(unsigned long long*)(dst + q * 8) = *(const unsigned long long*)(src + q * 8);
  }
}

// ------------- edge logits: 4 edges per wave (16 lanes each, int4 loads) -----
// x row n = [x_l(n) 1536 | x_r(n) 1536] fp8 e4m3, stride 3072 bytes.
// Per 16-lane group: lane reads 6 x int4 per side (96B) at cc = it*256+l16*16;
// its 0..2 lie wholly in head 0 (max byte 752 < 768), its 3..5 in head 1 --
// no mid-chunk head split.  xor-reduce with offsets <=8 stays in-group.
__global__ __launch_bounds__(256) void edge_logits(
    const unsigned char* __restrict__ x,
    const int* __restrict__ edges, const float* __restrict__ att,
    float* __restrict__ wbuf, float* __restrict__ denom) {
  int wave = (int)((blockIdx.x * blockDim.x + threadIdx.x) >> 6);
  int lane = threadIdx.x & 63;
  int e = wave * 4 + (lane >> 4);      // ETOT % 4 == 0 -> always valid
  if (e >= ETOT) return;
  int src, dst;
  if (e < EE) {
    src = edges[e];
    dst = edges[EE + e];
  } else {
    src = dst = e - EE;
  }
  const unsigned char* pl = x + (size_t)src * GNF;          // x_l[src]
  const unsigned char* pr = x + (size_t)dst * GNF + HC;     // x_r[dst]
  int l16 = lane & 15;
  float s0 = 0.f, s1 = 0.f;
#pragma unroll
  for (int it = 0; it < 6; ++it) {
    int cc = it * 256 + l16 * 16;      // byte offset (= att float index)
    int4 al = *(const int4*)(pl + cc);
    int4 ar = *(const int4*)(pr + cc);
    float4 w0 = *(const float4*)(att + cc);
    float4 w1 = *(const float4*)(att + cc + 4);
    float4 w2 = *(const float4*)(att + cc + 8);
    float4 w3 = *(const float4*)(att + cc + 12);
    float acc = 0.f;
#define E4(ai, ri, wv_) {                                               \
      float e0 = __builtin_amdgcn_cvt_f32_fp8(ai, 0) + __builtin_amdgcn_cvt_f32_fp8(ri, 0); \
      float e1 = __builtin_amdgcn_cvt_f32_fp8(ai, 1) + __builtin_amdgcn_cvt_f32_fp8(ri, 1); \
      float e2 = __builtin_amdgcn_cvt_f32_fp8(ai, 2) + __builtin_amdgcn_cvt_f32_fp8(ri, 2); \
      float e3 = __builtin_amdgcn_cvt_f32_fp8(ai, 3) + __builtin_amdgcn_cvt_f32_fp8(ri, 3); \
      e0 = e0 >= 0.f ? e0 : NEG_SLOPE * e0;                             \
      e1 = e1 >= 0.f ? e1 : NEG_SLOPE * e1;                             \
      e2 = e2 >= 0.f ? e2 : NEG_SLOPE * e2;                             \
      e3 = e3 >= 0.f ? e3 : NEG_SLOPE * e3;                             \
      acc += e0 * wv_.x + e1 * wv_.y + e2 * wv_.z + e3 * wv_.w; }
    E4(al.x, ar.x, w0);
    E4(al.y, ar.y, w1);
    E4(al.z, ar.z, w2);
    E4(al.w, ar.w, w3);
#undef E4
    if (it < 3) s0 += acc; else s1 += acc;
  }
  // reduce within each 16-lane group (xor masks <= 8 stay in-group)
#pragma unroll
  for (int off = 8; off; off >>= 1) {
    s0 += __shfl_xor(s0, off);
    s1 += __shfl_xor(s1, off);
  }
  if (l16 == 0) {
    float w0 = expf(s0), w1 = expf(s1);
    wbuf[(size_t)e * 2 + 0] = w0;
    wbuf[(size_t)e * 2 + 1] = w1;
    atomicAdd(&denom[(size_t)dst * 2 + 0], w0);
    atomicAdd(&denom[(size_t)dst * 2 + 1], w1);
  }
}

// ------------- alpha -> per-source scalar coefficients (masked by dst) -------
__global__ __launch_bounds__(256) void alpha_scatter(
    const int* __restrict__ edges, const int* __restrict__ mask,
    const float* __restrict__ wbuf, const float* __restrict__ denom,
    float* __restrict__ c) {
  int e = blockIdx.x * blockDim.x + threadIdx.x;
  if (e >= ETOT) return;
  int src, dst;
  if (e < EE) {
    src = edges[e];
    dst = edges[EE + e];
  } else {
    src = dst = e - EE;
  }
  if (mask[dst]) {
    atomicAdd(&c[(size_t)src * 2 + 0], wbuf[(size_t)e * 2 + 0] / denom[(size_t)dst * 2 + 0]);
    atomicAdd(&c[(size_t)src * 2 + 1], wbuf[(size_t)e * 2 + 1] / denom[(size_t)dst * 2 + 1]);
  }
}

// ------------- t[h,k] = sum_n c[n,h] * emb[n,k]  (f32 emb, coalesced) --------
__global__ __launch_bounds__(256) void c_emb_gemv(
    const float* __restrict__ emb, const float* __restrict__ c,
    float* __restrict__ t) {
  int tid = threadIdx.x;   // 256
  int b = blockIdx.x;      // 256 blocks x 128 rows
  float a0[3] = {}, a1[3] = {};
  int n0 = b * 128;
  for (int r = 0; r < 128; ++r) {
    int n = n0 + r;
    float c0 = c[(size_t)n * 2 + 0];
    float c1 = c[(size_t)n * 2 + 1];
    const float* row = emb + (size_t)n * GK;
#pragma unroll
    for (int k = 0; k < 3; ++k) {
      float v = row[tid + k * 256];
      a0[k] += c0 * v;
      a1[k] += c1 * v;
    }
  }
#pragma unroll
  for (int k = 0; k < 3; ++k) {
    atomicAdd(&t[tid + k * 256], a0[k]);
    atomicAdd(&t[HH + tid + k * 256], a1[k]);
  }
}

// ------------- pooled[h*768+d] = sum_k t[h,k] * W_l[k, h*768+d] --------------
// 12-way k-split (72 blocks; pooled pre-zeroed by prep) for CU parallelism.
__global__ __launch_bounds__(256) void pooled_gemv(
    const float* __restrict__ t, const float* __restrict__ W_l,
    float* __restrict__ pooled) {
  int idx = (blockIdx.x % 6) * 256 + threadIdx.x;   // 0..1535
  int ks = blockIdx.x / 6;                          // 0..11
  int h = idx / HH;
  float s = 0.f;
  const float* tp = t + (size_t)h * HH;
  const float* wp = W_l + idx;
  for (int k = ks * 64; k < (ks + 1) * 64; ++k) s += tp[k] * wp[(size_t)k * HC];
  atomicAdd(&pooled[idx], s);
}

// ------------- finalize: sum partials -> cnt; psy -> classifier -> outputs ---
__global__ __launch_bounds__(64) void finalize(
    const float* __restrict__ pooled, const float* __restrict__ partials,
    const float* __restrict__ bias, const float* __restrict__ clsW,
    const float* __restrict__ clsb, const int* __restrict__ labels,
    float* __restrict__ out) {
  int lane = threadIdx.x;  // 64
  float cs = 0.f;
  for (int i = lane; i < EBLK; i += 64) cs += partials[i];
#pragma unroll
  for (int off = 32; off; off >>= 1) cs += __shfl_down(cs, off);
  float cnt = __shfl(cs, 0);
  float inv = 1.f / (cnt + 1e-8f);
  __shared__ float lin[8];
  for (int lo = 0; lo < 8; ++lo) {
    int l = lo >> 1, o = lo & 1;
    float s = 0.f;
    for (int d = lane; d < HH; d += 64) {
      float psy = (0.5f * (pooled[d] + pooled[HH + d]) + cnt * bias[d]) * inv;
      s += psy * clsW[(size_t)l * HH * 2 + (size_t)d * 2 + o];
    }
#pragma unroll
    for (int off = 32; off; off >>= 1) s += __shfl_down(s, off);
    if (lane == 0) lin[lo] = s + clsb[lo];
  }
  __syncthreads();
  if (lane == 0) {
    float loss = 0.f, accv = 0.f;
    for (int l = 0; l < 4; ++l) {
      float a = lin[l * 2], bb = lin[l * 2 + 1];
      float m = fmaxf(a, bb);
      float ea = expf(a - m), eb = expf(bb - m);
      float inv2 = 1.f / (ea + eb);
      float p0 = ea * inv2, p1 = eb * inv2;
      // reference applies log_softmax to the PROBS (double-softmax quirk)
      float m2 = fmaxf(p0, p1);
      float lse = m2 + logf(expf(p0 - m2) + expf(p1 - m2));
      float lp0 = p0 - lse, lp1 = p1 - lse;
      int lab = labels[l];
      loss -= (lab == 1) ? lp1 : lp0;
      int pred = (p1 > p0) ? 1 : 0;  // argmax: first index on tie
      out[1 + l] = (float)pred;
      accv += (pred == lab) ? 1.f : 0.f;
    }
    out[0] = loss;
    out[5] = accv;
  }
}

// ---------------------------------------------------------------------------
extern "C" void kernel_launch(void* const* d_in, const int* in_sizes, int n_in,
                              void* d_out, int out_size, void* d_ws, size_t ws_size,
                              hipStream_t stream) {
  const float* emb   = (const float*)d_in[0];
  const int*   mask  = (const int*)d_in[1];
  const int*   edges = (const int*)d_in[2];
  const int*   labels= (const int*)d_in[3];
  const float* W_l   = (const float*)d_in[4];
  const float* W_r   = (const float*)d_in[5];
  const float* att   = (const float*)d_in[6];
  const float* gbias = (const float*)d_in[7];
  const float* clsW  = (const float*)d_in[8];
  const float* clsb  = (const float*)d_in[9];
  float* out = (float*)d_out;

  // workspace (~130 MB; ws proven >= 258 MB by rounds 5-19):
  unsigned char*  B8c = (unsigned char*)d_ws;                 // 48*3072*16
  unsigned char*  A8c = B8c + (size_t)NCH * GNF * 16;         // 48*32768*16
  unsigned char*  x   = A8c + (size_t)NCH * NN * 16;          // NN*3072 fp8
  float* fregion = (float*)(x + (size_t)NN * GNF);
  float* wbuf     = fregion;                       // ETOT*2
  float* denom    = wbuf + (size_t)ETOT * 2;       // NN*2
  float* c        = denom + (size_t)NN * 2;        // NN*2
  float* t        = c + (size_t)NN * 2;            // HC
  float* pooled   = t + HC;                        // HC
  float* partials = pooled + HC;                   // EBLK
  int zero_count = (int)(NN * 2 + NN * 2 + HC + HC);  // denom..pooled

  // 0) fused prep: W chunking | emb chunking + zeroing + mask partial counts
  prep<<<2 * WBLK + EBLK, 256, 0, stream>>>(
      W_l, W_r, emb, mask, B8c, A8c, denom, zero_count, partials);

  // 1) x = emb8 @ Wt8^T   (barrier-free reg-streamed MX-fp8, 64x128 wave tile)
  gemm_fp8<<<(NN / 128) * (GNF / 256), 256, 0, stream>>>(A8c, B8c, x);

  // 2) edge logits + denom  (4 edges/wave, int4 x-loads)
  edge_logits<<<ETOT / 16, 256, 0, stream>>>(x, edges, att, wbuf, denom);

  // 3) alpha -> c[src,h]
  alpha_scatter<<<(ETOT + 255) / 256, 256, 0, stream>>>(edges, mask, wbuf, denom, c);

  // 4) t = c^T @ emb  [2,768]  (exact fp32, coalesced)
  c_emb_gemv<<<NN / 128, 256, 0, stream>>>(emb, c, t);

  // 5) pooled = t @ W_l (per-head slice, exact fp32, 12-way k-split)
  pooled_gemv<<<72, 256, 0, stream>>>(t, W_l, pooled);

  // 6) finalize (also reduces mask partials -> cnt)
  finalize<<<1, 64, 0, stream>>>(pooled, partials, gbias, clsW, clsb, labels, out);
}

// Round 21
// 255.163 us; speedup vs baseline: 1.0118x; 1.0118x over previous
//
#include <hip/hip_runtime.h>
#include <hip/hip_bf16.h>

// Problem dims (fixed by reference setup_inputs)
#define NN 32768
#define HH 768
#define HEADS 2
#define EE 131072
#define HC (HEADS*HH)      // 1536
#define ETOT (EE + NN)     // 163840 (edges + self loops)
#define NEG_SLOPE 0.2f
#define GK 768             // GEMM K
#define GNF 3072           // fused GEMM N ([W_l | W_r] cols)
#define NCH (GK/16)        // 48 k-chunks of 16 bytes
#define WBLK 1152          // W-role blocks per weight (48 n-tiles x 24 k-tiles)
#define EBLK 1792          // emb-role blocks

typedef float f32x16 __attribute__((ext_vector_type(16)));
typedef int i32x8 __attribute__((ext_vector_type(8)));

// ======== fused prep: W_l-chunk | W_r-chunk | emb-chunk + zero + mask-count ==
__global__ __launch_bounds__(256) void prep(
    const float* __restrict__ W_l, const float* __restrict__ W_r,
    const float* __restrict__ emb, const int* __restrict__ mask,
    unsigned char* __restrict__ B8c, unsigned char* __restrict__ A8c,
    float* __restrict__ zbase, int nz, float* __restrict__ partials) {
  int b = blockIdx.x, tid = threadIdx.x;
  if (b < 2 * WBLK) {
    // ---- W role (transpose+convert to chunked fp8) ----
    const float* W = (b < WBLK) ? W_l : W_r;
    int coff = (b < WBLK) ? 0 : HC;
    int b2 = (b < WBLK) ? b : b - WBLK;
    __shared__ float tile[32][33];
    int n0 = (b2 % 48) * 32, k0 = (b2 / 48) * 32;
    int tx = tid & 31, ty = tid >> 5;  // 32 x 8
#pragma unroll
    for (int s = 0; s < 4; ++s)
      tile[ty + s * 8][tx] = W[(size_t)(k0 + ty + s * 8) * HC + n0 + tx];
    __syncthreads();
#pragma unroll
    for (int s = 0; s < 4; ++s) {
      int k = k0 + tx, n = n0 + ty + s * 8;
      int pk = __builtin_amdgcn_cvt_pk_fp8_f32(tile[tx][ty + s * 8], 0.f, 0, false);
      B8c[((size_t)(k >> 4) * GNF + coff + n) * 16 + (k & 15)] = (unsigned char)(pk & 0xff);
    }
    return;
  }
  // ---- emb role ----
  int ridx = b - 2 * WBLK;
  int i0 = ridx * 256 + tid;
  const int st = EBLK * 256;
  const int total = NN * NCH;
  for (int i = i0; i < total; i += st) {
    int n = i & (NN - 1), q = i >> 15;
    const float* src = emb + (size_t)n * GK + q * 16;
    float4 a = *(const float4*)(src);
    float4 bb = *(const float4*)(src + 4);
    float4 c = *(const float4*)(src + 8);
    float4 d = *(const float4*)(src + 12);
    int pk0 = 0, pk1 = 0, pk2 = 0, pk3 = 0;
    pk0 = __builtin_amdgcn_cvt_pk_fp8_f32(a.x, a.y, pk0, false);
    pk0 = __builtin_amdgcn_cvt_pk_fp8_f32(a.z, a.w, pk0, true);
    pk1 = __builtin_amdgcn_cvt_pk_fp8_f32(bb.x, bb.y, pk1, false);
    pk1 = __builtin_amdgcn_cvt_pk_fp8_f32(bb.z, bb.w, pk1, true);
    pk2 = __builtin_amdgcn_cvt_pk_fp8_f32(c.x, c.y, pk2, false);
    pk2 = __builtin_amdgcn_cvt_pk_fp8_f32(c.z, c.w, pk2, true);
    pk3 = __builtin_amdgcn_cvt_pk_fp8_f32(d.x, d.y, pk3, false);
    pk3 = __builtin_amdgcn_cvt_pk_fp8_f32(d.z, d.w, pk3, true);
    int4 pk; pk.x = pk0; pk.y = pk1; pk.z = pk2; pk.w = pk3;
    *(int4*)(A8c + (size_t)i * 16) = pk;
  }
  for (int i = i0; i < nz; i += st) zbase[i] = 0.f;
  float local = 0.f;
  for (int i = i0; i < NN; i += st) local += (mask[i] != 0) ? 1.f : 0.f;
#pragma unroll
  for (int off = 32; off; off >>= 1) local += __shfl_down(local, off);
  __shared__ float wsum[4];
  if ((tid & 63) == 0) wsum[tid >> 6] = local;
  __syncthreads();
  if (tid == 0) partials[ridx] = wsum[0] + wsum[1] + wsum[2] + wsum[3];
}

// ======== GEMM (MX-fp8, barrier-free, 64x128 wave tile): control, R16 ========
__global__ __launch_bounds__(256) void gemm_fp8(
    const unsigned char* __restrict__ Ac, const unsigned char* __restrict__ Bc,
    unsigned char* __restrict__ X) {
  __shared__ unsigned char cb[128 * 264];
  int tid = threadIdx.x, lane = tid & 63, wv = tid >> 6;
  int wvr = wv >> 1, wvc = wv & 1;
  int b = blockIdx.x;
  int xcd = b & 7, loc = b >> 3;        // loc 0..383
  int m_blk = xcd * 32 + loc / 12, n_blk = loc % 12;
  int m0 = m_blk * 128, n0 = n_blk * 256;

  int qb = (lane >> 5) * 2;
  int arow = m0 + wvr * 64 + (lane & 31);
  int brow = n0 + wvc * 128 + (lane & 31);
  const unsigned char* pA = Ac + ((size_t)qb * NN + arow) * 16;
  const unsigned char* pB = Bc + ((size_t)qb * GNF + brow) * 16;
  const size_t stA = (size_t)4 * NN * 16;
  const size_t stB = (size_t)4 * GNF * 16;

  int4 bA[2][2][2], bB[2][4][2];
  f32x16 acc[2][4] = {};

#define ISSUE(pp_, it_) {                                               \
    const unsigned char* a_ = pA + (size_t)(it_) * stA;                 \
    const unsigned char* b_ = pB + (size_t)(it_) * stB;                 \
    _Pragma("unroll") for (int mg = 0; mg < 2; ++mg) {                  \
      bA[pp_][mg][0] = *(const int4*)(a_ + mg * 512);                   \
      bA[pp_][mg][1] = *(const int4*)(a_ + mg * 512 + (size_t)NN * 16); } \
    _Pragma("unroll") for (int ng = 0; ng < 4; ++ng) {                  \
      bB[pp_][ng][0] = *(const int4*)(b_ + ng * 512);                   \
      bB[pp_][ng][1] = *(const int4*)(b_ + ng * 512 + (size_t)GNF * 16); } }

#define MM(pp_) {                                                       \
    i32x8 bfr[4];                                                       \
    _Pragma("unroll") for (int ng = 0; ng < 4; ++ng) {                  \
      bfr[ng][0] = bB[pp_][ng][0].x; bfr[ng][1] = bB[pp_][ng][0].y;     \
      bfr[ng][2] = bB[pp_][ng][0].z; bfr[ng][3] = bB[pp_][ng][0].w;     \
      bfr[ng][4] = bB[pp_][ng][1].x; bfr[ng][5] = bB[pp_][ng][1].y;     \
      bfr[ng][6] = bB[pp_][ng][1].z; bfr[ng][7] = bB[pp_][ng][1].w; }   \
    _Pragma("unroll") for (int mg = 0; mg < 2; ++mg) {                  \
      i32x8 af;                                                         \
      af[0] = bA[pp_][mg][0].x; af[1] = bA[pp_][mg][0].y;               \
      af[2] = bA[pp_][mg][0].z; af[3] = bA[pp_][mg][0].w;               \
      af[4] = bA[pp_][mg][1].x; af[5] = bA[pp_][mg][1].y;               \
      af[6] = bA[pp_][mg][1].z; af[7] = bA[pp_][mg][1].w;               \
      _Pragma("unroll") for (int ng = 0; ng < 4; ++ng)                  \
        acc[mg][ng] = __builtin_amdgcn_mfma_scale_f32_32x32x64_f8f6f4(  \
            bfr[ng], af, acc[mg][ng], 0, 0,                             \
            0, 0x7F7F7F7F, 0, 0x7F7F7F7F); } }

  ISSUE(0, 0);
  ISSUE(1, 1);
#pragma unroll
  for (int t = 0; t < 12; ++t) {
    const int pp = t & 1;
    MM(pp);
    if (t + 2 < 12) ISSUE(pp, t + 2);
  }
#undef ISSUE
#undef MM

#pragma unroll
  for (int mg = 0; mg < 2; ++mg) {
    int m = wvr * 64 + mg * 32 + (lane & 31);
#pragma unroll
    for (int ng = 0; ng < 4; ++ng) {
      int nb = wvc * 128 + ng * 32 + (lane >> 5) * 4;
#pragma unroll
      for (int rq = 0; rq < 4; ++rq) {
        int pk = 0;
        pk = __builtin_amdgcn_cvt_pk_fp8_f32(acc[mg][ng][rq * 4 + 0],
                                             acc[mg][ng][rq * 4 + 1], pk, false);
        pk = __builtin_amdgcn_cvt_pk_fp8_f32(acc[mg][ng][rq * 4 + 2],
                                             acc[mg][ng][rq * 4 + 3], pk, true);
        *(int*)&cb[m * 264 + nb + rq * 8] = pk;
      }
    }
  }
  __syncthreads();
  {
    int r = tid >> 1, hf = tid & 1;
    const unsigned char* src = &cb[r * 264 + hf * 128];
    unsigned char* dst = X + (size_t)(m0 + r) * GNF + n0 + hf * 128;
#pragma unroll
    for (int q = 0; q < 16; ++q)
      *(unsigned long long*)(dst + q * 8) = *(const unsigned long long*)(src + q * 8);
  }
}

// ------------- edge logits: 2 edges per wave (32 lanes each, int4 loads) -----
// R19-proven best (255.9 us total).  x row n = [x_l 1536 | x_r 1536] fp8.
// Per 32-lane group: lane reads 3 x int4 per side (48B); head split:
// it0 -> h0, it2 -> h1, it1 splits at (lane&31)==16 (byte 768 boundary).
__global__ __launch_bounds__(256) void edge_logits(
    const unsigned char* __restrict__ x,
    const int* __restrict__ edges, const float* __restrict__ att,
    float* __restrict__ wbuf, float* __restrict__ denom) {
  int wave = (int)((blockIdx.x * blockDim.x + threadIdx.x) >> 6);
  int lane = threadIdx.x & 63;
  int e = wave * 2 + (lane >> 5);      // ETOT even -> always valid
  if (e >= ETOT) return;
  int src, dst;
  if (e < EE) {
    src = edges[e];
    dst = edges[EE + e];
  } else {
    src = dst = e - EE;
  }
  const unsigned char* pl = x + (size_t)src * GNF;          // x_l[src]
  const unsigned char* pr = x + (size_t)dst * GNF + HC;     // x_r[dst]
  int l32 = lane & 31;
  float s0 = 0.f, s1 = 0.f;
#pragma unroll
  for (int it = 0; it < 3; ++it) {
    int cc = it * 512 + l32 * 16;      // byte offset (= att float index)
    int4 al = *(const int4*)(pl + cc);
    int4 ar = *(const int4*)(pr + cc);
    float4 w0 = *(const float4*)(att + cc);
    float4 w1 = *(const float4*)(att + cc + 4);
    float4 w2 = *(const float4*)(att + cc + 8);
    float4 w3 = *(const float4*)(att + cc + 12);
    float acc = 0.f;
#define E4(ai, ri, wv_) {                                               \
      float e0 = __builtin_amdgcn_cvt_f32_fp8(ai, 0) + __builtin_amdgcn_cvt_f32_fp8(ri, 0); \
      float e1 = __builtin_amdgcn_cvt_f32_fp8(ai, 1) + __builtin_amdgcn_cvt_f32_fp8(ri, 1); \
      float e2 = __builtin_amdgcn_cvt_f32_fp8(ai, 2) + __builtin_amdgcn_cvt_f32_fp8(ri, 2); \
      float e3 = __builtin_amdgcn_cvt_f32_fp8(ai, 3) + __builtin_amdgcn_cvt_f32_fp8(ri, 3); \
      e0 = e0 >= 0.f ? e0 : NEG_SLOPE * e0;                             \
      e1 = e1 >= 0.f ? e1 : NEG_SLOPE * e1;                             \
      e2 = e2 >= 0.f ? e2 : NEG_SLOPE * e2;                             \
      e3 = e3 >= 0.f ? e3 : NEG_SLOPE * e3;                             \
      acc += e0 * wv_.x + e1 * wv_.y + e2 * wv_.z + e3 * wv_.w; }
    E4(al.x, ar.x, w0);
    E4(al.y, ar.y, w1);
    E4(al.z, ar.z, w2);
    E4(al.w, ar.w, w3);
#undef E4
    if (it == 0) s0 += acc;
    else if (it == 2) s1 += acc;
    else { if (l32 < 16) s0 += acc; else s1 += acc; }
  }
  // reduce within each 32-lane group (xor masks <= 16 stay in-group)
#pragma unroll
  for (int off = 16; off; off >>= 1) {
    s0 += __shfl_xor(s0, off);
    s1 += __shfl_xor(s1, off);
  }
  if (l32 == 0) {
    float w0 = expf(s0), w1 = expf(s1);
    wbuf[(size_t)e * 2 + 0] = w0;
    wbuf[(size_t)e * 2 + 1] = w1;
    atomicAdd(&denom[(size_t)dst * 2 + 0], w0);
    atomicAdd(&denom[(size_t)dst * 2 + 1], w1);
  }
}

// ------------- alpha -> per-source scalar coefficients (masked by dst) -------
__global__ __launch_bounds__(256) void alpha_scatter(
    const int* __restrict__ edges, const int* __restrict__ mask,
    const float* __restrict__ wbuf, const float* __restrict__ denom,
    float* __restrict__ c) {
  int e = blockIdx.x * blockDim.x + threadIdx.x;
  if (e >= ETOT) return;
  int src, dst;
  if (e < EE) {
    src = edges[e];
    dst = edges[EE + e];
  } else {
    src = dst = e - EE;
  }
  if (mask[dst]) {
    atomicAdd(&c[(size_t)src * 2 + 0], wbuf[(size_t)e * 2 + 0] / denom[(size_t)dst * 2 + 0]);
    atomicAdd(&c[(size_t)src * 2 + 1], wbuf[(size_t)e * 2 + 1] / denom[(size_t)dst * 2 + 1]);
  }
}

// ------------- t[h,k] = sum_n c[n,h] * emb[n,k]  (f32 emb, coalesced) --------
__global__ __launch_bounds__(256) void c_emb_gemv(
    const float* __restrict__ emb, const float* __restrict__ c,
    float* __restrict__ t) {
  int tid = threadIdx.x;   // 256
  int b = blockIdx.x;      // 256 blocks x 128 rows
  float a0[3] = {}, a1[3] = {};
  int n0 = b * 128;
  for (int r = 0; r < 128; ++r) {
    int n = n0 + r;
    float c0 = c[(size_t)n * 2 + 0];
    float c1 = c[(size_t)n * 2 + 1];
    const float* row = emb + (size_t)n * GK;
#pragma unroll
    for (int k = 0; k < 3; ++k) {
      float v = row[tid + k * 256];
      a0[k] += c0 * v;
      a1[k] += c1 * v;
    }
  }
#pragma unroll
  for (int k = 0; k < 3; ++k) {
    atomicAdd(&t[tid + k * 256], a0[k]);
    atomicAdd(&t[HH + tid + k * 256], a1[k]);
  }
}

// ------------- pooled[h*768+d] = sum_k t[h,k] * W_l[k, h*768+d] --------------
// 12-way k-split (72 blocks; pooled pre-zeroed by prep) for CU parallelism.
__global__ __launch_bounds__(256) void pooled_gemv(
    const float* __restrict__ t, const float* __restrict__ W_l,
    float* __restrict__ pooled) {
  int idx = (blockIdx.x % 6) * 256 + threadIdx.x;   // 0..1535
  int ks = blockIdx.x / 6;                          // 0..11
  int h = idx / HH;
  float s = 0.f;
  const float* tp = t + (size_t)h * HH;
  const float* wp = W_l + idx;
  for (int k = ks * 64; k < (ks + 1) * 64; ++k) s += tp[k] * wp[(size_t)k * HC];
  atomicAdd(&pooled[idx], s);
}

// ------------- finalize: sum partials -> cnt; psy -> classifier -> outputs ---
__global__ __launch_bounds__(64) void finalize(
    const float* __restrict__ pooled, const float* __restrict__ partials,
    const float* __restrict__ bias, const float* __restrict__ clsW,
    const float* __restrict__ clsb, const int* __restrict__ labels,
    float* __restrict__ out) {
  int lane = threadIdx.x;  // 64
  float cs = 0.f;
  for (int i = lane; i < EBLK; i += 64) cs += partials[i];
#pragma unroll
  for (int off = 32; off; off >>= 1) cs += __shfl_down(cs, off);
  float cnt = __shfl(cs, 0);
  float inv = 1.f / (cnt + 1e-8f);
  __shared__ float lin[8];
  for (int lo = 0; lo < 8; ++lo) {
    int l = lo >> 1, o = lo & 1;
    float s = 0.f;
    for (int d = lane; d < HH; d += 64) {
      float psy = (0.5f * (pooled[d] + pooled[HH + d]) + cnt * bias[d]) * inv;
      s += psy * clsW[(size_t)l * HH * 2 + (size_t)d * 2 + o];
    }
#pragma unroll
    for (int off = 32; off; off >>= 1) s += __shfl_down(s, off);
    if (lane == 0) lin[lo] = s + clsb[lo];
  }
  __syncthreads();
  if (lane == 0) {
    float loss = 0.f, accv = 0.f;
    for (int l = 0; l < 4; ++l) {
      float a = lin[l * 2], bb = lin[l * 2 + 1];
      float m = fmaxf(a, bb);
      float ea = expf(a - m), eb = expf(bb - m);
      float inv2 = 1.f / (ea + eb);
      float p0 = ea * inv2, p1 = eb * inv2;
      // reference applies log_softmax to the PROBS (double-softmax quirk)
      float m2 = fmaxf(p0, p1);
      float lse = m2 + logf(expf(p0 - m2) + expf(p1 - m2));
      float lp0 = p0 - lse, lp1 = p1 - lse;
      int lab = labels[l];
      loss -= (lab == 1) ? lp1 : lp0;
      int pred = (p1 > p0) ? 1 : 0;  // argmax: first index on tie
      out[1 + l] = (float)pred;
      accv += (pred == lab) ? 1.f : 0.f;
    }
    out[0] = loss;
    out[5] = accv;
  }
}

// ---------------------------------------------------------------------------
extern "C" void kernel_launch(void* const* d_in, const int* in_sizes, int n_in,
                              void* d_out, int out_size, void* d_ws, size_t ws_size,
                              hipStream_t stream) {
  const float* emb   = (const float*)d_in[0];
  const int*   mask  = (const int*)d_in[1];
  const int*   edges = (const int*)d_in[2];
  const int*   labels= (const int*)d_in[3];
  const float* W_l   = (const float*)d_in[4];
  const float* W_r   = (const float*)d_in[5];
  const float* att   = (const float*)d_in[6];
  const float* gbias = (const float*)d_in[7];
  const float* clsW  = (const float*)d_in[8];
  const float* clsb  = (const float*)d_in[9];
  float* out = (float*)d_out;

  // workspace (~130 MB; ws proven >= 258 MB by rounds 5-20):
  unsigned char*  B8c = (unsigned char*)d_ws;                 // 48*3072*16
  unsigned char*  A8c = B8c + (size_t)NCH * GNF * 16;         // 48*32768*16
  unsigned char*  x   = A8c + (size_t)NCH * NN * 16;          // NN*3072 fp8
  float* fregion = (float*)(x + (size_t)NN * GNF);
  float* wbuf     = fregion;                       // ETOT*2
  float* denom    = wbuf + (size_t)ETOT * 2;       // NN*2
  float* c        = denom + (size_t)NN * 2;        // NN*2
  float* t        = c + (size_t)NN * 2;            // HC
  float* pooled   = t + HC;                        // HC
  float* partials = pooled + HC;                   // EBLK
  int zero_count = (int)(NN * 2 + NN * 2 + HC + HC);  // denom..pooled

  // 0) fused prep: W chunking | emb chunking + zeroing + mask partial counts
  prep<<<2 * WBLK + EBLK, 256, 0, stream>>>(
      W_l, W_r, emb, mask, B8c, A8c, denom, zero_count, partials);

  // 1) x = emb8 @ Wt8^T   (barrier-free reg-streamed MX-fp8, 64x128 wave tile)
  gemm_fp8<<<(NN / 128) * (GNF / 256), 256, 0, stream>>>(A8c, B8c, x);

  // 2) edge logits + denom  (2 edges/wave, int4 x-loads; R19-proven best)
  edge_logits<<<ETOT / 8, 256, 0, stream>>>(x, edges, att, wbuf, denom);

  // 3) alpha -> c[src,h]
  alpha_scatter<<<(ETOT + 255) / 256, 256, 0, stream>>>(edges, mask, wbuf, denom, c);

  // 4) t = c^T @ emb  [2,768]  (exact fp32, coalesced)
  c_emb_gemv<<<NN / 128, 256, 0, stream>>>(emb, c, t);

  // 5) pooled = t @ W_l (per-head slice, exact fp32, 12-way k-split)
  pooled_gemv<<<72, 256, 0, stream>>>(t, W_l, pooled);

  // 6) finalize (also reduces mask partials -> cnt)
  finalize<<<1, 64, 0, stream>>>(pooled, partials, gbias, clsW, clsb, labels, out);
}